// Round 26
// baseline (385.964 us; speedup 1.0000x reference)
//
#include <hip/hip_runtime.h>
#include <hip/hip_bf16.h>

// ---------------------------------------------------------------------------
// GAT 2-layer, N=16384 nodes, D=512, H=8, E=524288 edges (+self loops)
// GEMM0: split-bf16 3-term MFMA (BK=32), fused alpha0, bf16 h0 out.
// GEMM1: pure bf16 MFMA, BK=64. Both: bijective XCD tile remap.
// Node kernels: one wave/node, batched two-pass softmax, packed f32x2 FMA,
// HOISTED alpha staging (all chunks written before aggregate loop -> no
// LDS WAR serialization; gathers pipeline across all edges).
// ---------------------------------------------------------------------------

#define NNODES 16384
#define MXIT 12   // supports node degree up to 95; guarded tail beyond

typedef unsigned short u16;
typedef unsigned int u32;
typedef __attribute__((ext_vector_type(8))) __bf16 bf16x8;
typedef __attribute__((ext_vector_type(4))) float f32x4;
typedef __attribute__((ext_vector_type(2))) float f32x2;

__device__ __forceinline__ u16 f2bf(float v) {
    u32 u = __builtin_bit_cast(u32, v);
    u32 r = (u + 0x7fffu + ((u >> 16) & 1u)) >> 16;
    return (u16)r;
}
__device__ __forceinline__ float bf2f(u16 s) {
    u32 u = ((u32)s) << 16;
    return __builtin_bit_cast(float, u);
}
__device__ __forceinline__ float bflo(u32 u) {
    return __builtin_bit_cast(float, u << 16);
}
__device__ __forceinline__ float bfhi(u32 u) {
    return __builtin_bit_cast(float, u & 0xffff0000u);
}
__device__ __forceinline__ void split2(float v, u16& h, u16& l) {
    h = f2bf(v);
    l = f2bf(v - bf2f(h));
}
__device__ __forceinline__ u32 pack2(float a, float b) {
    return (u32)f2bf(a) | ((u32)f2bf(b) << 16);
}
__device__ __forceinline__ f32x2 pkfma(f32x2 a, f32x2 b, f32x2 c) {
    return __builtin_elementwise_fma(a, b, c);
}

// async global->LDS, 16B per lane
__device__ __forceinline__ void gload_lds16(const u16* g, u16* l) {
    __builtin_amdgcn_global_load_lds(
        (__attribute__((address_space(1))) void*)(void*)(g),
        (__attribute__((address_space(3))) void*)(void*)(l), 16, 0, 0);
}

// ------------------------------ CSR build ---------------------------------
__global__ void zero_k(int* p, int n) {
    int i = blockIdx.x * 256 + threadIdx.x;
    if (i < n) p[i] = 0;
}

__global__ void count_k(const int* __restrict__ dst, int E, int* __restrict__ deg) {
    int i = blockIdx.x * 256 + threadIdx.x;
    if (i < E) atomicAdd(&deg[dst[i]], 1);
}

__global__ __launch_bounds__(1024) void scan_k(const int* __restrict__ deg,
                                               int* __restrict__ indptr,
                                               int* __restrict__ cursor, int n) {
    __shared__ int sums[1024];
    int t = threadIdx.x;
    int base = t * 16;
    int local[16];
    int s = 0;
    #pragma unroll
    for (int i = 0; i < 16; i++) { local[i] = s; s += deg[base + i]; }
    sums[t] = s;
    __syncthreads();
    for (int off = 1; off < 1024; off <<= 1) {
        int v = (t >= off) ? sums[t - off] : 0;
        __syncthreads();
        sums[t] += v;
        __syncthreads();
    }
    int base_sum = (t == 0) ? 0 : sums[t - 1];
    #pragma unroll
    for (int i = 0; i < 16; i++) {
        int v = base_sum + local[i];
        indptr[base + i] = v;
        cursor[base + i] = v;
    }
    if (t == 1023) indptr[n] = base_sum + s;
}

__global__ void scatter_k(const int* __restrict__ src, const int* __restrict__ dst,
                          int E, int* __restrict__ cursor, int* __restrict__ csr) {
    int i = blockIdx.x * 256 + threadIdx.x;
    if (i < E) {
        int pos = atomicAdd(&cursor[dst[i]], 1);
        csr[pos] = src[i];
    }
}

// ------------------------- split-bf16 prep kernels -------------------------
__global__ void prepx_k(const float* __restrict__ x, u16* __restrict__ xh,
                        u16* __restrict__ xl) {
    int idx = blockIdx.x * 256 + threadIdx.x;
    int e = idx << 2;
    int n = e >> 9, k = e & 511;
    int g = n >> 10, s = n & 1023;
    float4 v = *(const float4*)(x + ((size_t)(s * 16 + g) << 9) + k);
    u16 h[4], l[4];
    split2(v.x, h[0], l[0]);
    split2(v.y, h[1], l[1]);
    split2(v.z, h[2], l[2]);
    split2(v.w, h[3], l[3]);
    size_t o = ((size_t)n << 9) + k;
    *(ushort4*)(xh + o) = make_ushort4(h[0], h[1], h[2], h[3]);
    *(ushort4*)(xl + o) = make_ushort4(l[0], l[1], l[2], l[3]);
}

// W0t[n][k] = W0[k][n], tiled 64x64 transpose through LDS
__global__ __launch_bounds__(256) void prepW0t_k(const float* __restrict__ W0,
                                                 u16* __restrict__ Wh,
                                                 u16* __restrict__ Wl) {
    __shared__ u32 tile[64][65];
    int b = blockIdx.x;
    int kt = (b >> 3) * 64, nt = (b & 7) * 64;
    int t = threadIdx.x;
    #pragma unroll
    for (int i = 0; i < 16; i++) {
        int idx = i * 256 + t;
        int r = idx >> 6, c = idx & 63;
        float v = W0[(size_t)(kt + r) * 512 + nt + c];
        u16 h, l;
        split2(v, h, l);
        tile[r][c] = ((u32)h << 16) | l;
    }
    __syncthreads();
    #pragma unroll
    for (int i = 0; i < 8; i++) {
        int idx = i * 256 + t;
        int r = idx >> 5, c2 = (idx & 31) * 2;
        u32 p0 = tile[c2][r], p1 = tile[c2 + 1][r];
        size_t o = (size_t)(nt + r) * 512 + kt + c2;
        *(ushort2*)(Wh + o) = make_ushort2((u16)(p0 >> 16), (u16)(p1 >> 16));
        *(ushort2*)(Wl + o) = make_ushort2((u16)(p0 & 0xffff), (u16)(p1 & 0xffff));
    }
}

// B1t[c][h*512+k] = bf16(W1[k][h*512+c]/8), per-head tiled 64x64 transpose
__global__ __launch_bounds__(256) void prepW1t_k(const float* __restrict__ W1,
                                                 u16* __restrict__ Bh) {
    __shared__ u16 tile[64][66];
    int b = blockIdx.x;
    int hh = b >> 6;
    int rem = b & 63;
    int kt = (rem >> 3) * 64, ct = (rem & 7) * 64;
    int t = threadIdx.x;
    #pragma unroll
    for (int i = 0; i < 16; i++) {
        int idx = i * 256 + t;
        int r = idx >> 6, c = idx & 63;
        float v = W1[(size_t)(kt + r) * 4096 + hh * 512 + ct + c] * 0.125f;
        tile[r][c] = f2bf(v);
    }
    __syncthreads();
    #pragma unroll
    for (int i = 0; i < 8; i++) {
        int idx = i * 256 + t;
        int r = idx >> 5, c2 = (idx & 31) * 2;
        size_t o = (size_t)(ct + r) * 4096 + hh * 512 + kt + c2;
        *(ushort2*)(Bh + o) = make_ushort2(tile[c2][r], tile[c2 + 1][r]);
    }
}

// ---------------------------------------------------------------------------
// MFMA GEMM: C[M,512] = A[M,K] @ Bt[512,K]^T, XCD-remapped tiles.
// TERMS=3: split-bf16 3-term, BK=32. TERMS=1: pure bf16, BK=64 (2 halves).
// MODE 1: f32 out, +bias, ELU. MODE 2: bf16 out + fused alpha0.
// ---------------------------------------------------------------------------
template <int MODE, int TERMS>
__global__ __launch_bounds__(256) void mgemm_k(
    const u16* __restrict__ Ah, const u16* __restrict__ Al,
    const u16* __restrict__ Bh, const u16* __restrict__ Bl,
    void* __restrict__ Cv, int K, const float* __restrict__ bias,
    const float* __restrict__ att_s, const float* __restrict__ att_d,
    float* __restrict__ as_, float* __restrict__ ad_) {
    __shared__ u16 smem[16384];  // 32 KB both variants

    int t = threadIdx.x;
    int lane = t & 63, w = t >> 6;
    int wr = w >> 1, wc = w & 1;

    // bijective XCD remap: all 4 col-tiles of a row-tile land on one XCD
    int orig = blockIdx.x + (blockIdx.y << 2);
    int xcd = orig & 7, slot = orig >> 3;
    int by = xcd * ((int)gridDim.y >> 3) + (slot >> 2);
    int bx = slot & 3;
    int row0 = by * 128, col0 = bx * 128;

    f32x4 acc[4][4];
    #pragma unroll
    for (int i = 0; i < 4; i++)
        #pragma unroll
        for (int j = 0; j < 4; j++) acc[i][j] = (f32x4){0.f, 0.f, 0.f, 0.f};

    int srow = lane >> 2;
    int sl4 = lane & 3;
    const u16* gp[8];
    u16* lp[8];
    #pragma unroll
    for (int ii = 0; ii < 8; ii++) {
        const u16* gb;
        int g0, koff;
        if (TERMS == 3) {
            gb = (w == 0) ? Ah : (w == 1) ? Al : (w == 2) ? Bh : Bl;
            g0 = (w < 2) ? row0 : col0;
            koff = 0;
        } else {
            gb = (w < 2) ? Ah : Bh;
            g0 = (w < 2) ? row0 : col0;
            koff = (w & 1) * 32;
        }
        int row = ii * 16 + srow;
        int sslot = sl4 ^ ((row >> 1) & 3);
        gp[ii] = gb + (size_t)(g0 + row) * K + koff + sslot * 8;
        lp[ii] = smem + w * 4096 + ii * 512;
    }

    int rl = lane & 15, kb = lane >> 4;

    if (TERMS == 3) {
        for (int k0 = 0; k0 < K; k0 += 32) {
            #pragma unroll
            for (int ii = 0; ii < 8; ii++) gload_lds16(gp[ii] + k0, lp[ii]);
            __syncthreads();

            bf16x8 afh[4], afl_[4], bfh[4], bfl[4];
            #pragma unroll
            for (int f = 0; f < 4; f++) {
                int r = wr * 64 + f * 16 + rl;
                int off = r * 32 + ((kb ^ ((r >> 1) & 3)) << 3);
                afh[f] = *(const bf16x8*)(smem + off);
                afl_[f] = *(const bf16x8*)(smem + 4096 + off);
            }
            #pragma unroll
            for (int j = 0; j < 4; j++) {
                int r = wc * 64 + j * 16 + rl;
                int off = r * 32 + ((kb ^ ((r >> 1) & 3)) << 3);
                bfh[j] = *(const bf16x8*)(smem + 8192 + off);
                bfl[j] = *(const bf16x8*)(smem + 12288 + off);
            }
            #pragma unroll
            for (int i = 0; i < 4; i++)
                #pragma unroll
                for (int j = 0; j < 4; j++) {
                    acc[i][j] = __builtin_amdgcn_mfma_f32_16x16x32_bf16(
                        afl_[i], bfh[j], acc[i][j], 0, 0, 0);
                    acc[i][j] = __builtin_amdgcn_mfma_f32_16x16x32_bf16(
                        afh[i], bfl[j], acc[i][j], 0, 0, 0);
                    acc[i][j] = __builtin_amdgcn_mfma_f32_16x16x32_bf16(
                        afh[i], bfh[j], acc[i][j], 0, 0, 0);
                }
            __syncthreads();
        }
    } else {
        for (int k0 = 0; k0 < K; k0 += 64) {
            #pragma unroll
            for (int ii = 0; ii < 8; ii++) gload_lds16(gp[ii] + k0, lp[ii]);
            __syncthreads();

            #pragma unroll
            for (int ks = 0; ks < 2; ks++) {
                bf16x8 af[4], bf[4];
                #pragma unroll
                for (int f = 0; f < 4; f++) {
                    int r = wr * 64 + f * 16 + rl;
                    int off = r * 32 + ((kb ^ ((r >> 1) & 3)) << 3);
                    af[f] = *(const bf16x8*)(smem + ks * 4096 + off);
                }
                #pragma unroll
                for (int j = 0; j < 4; j++) {
                    int r = wc * 64 + j * 16 + rl;
                    int off = r * 32 + ((kb ^ ((r >> 1) & 3)) << 3);
                    bf[j] = *(const bf16x8*)(smem + 8192 + ks * 4096 + off);
                }
                #pragma unroll
                for (int i = 0; i < 4; i++)
                    #pragma unroll
                    for (int j = 0; j < 4; j++)
                        acc[i][j] = __builtin_amdgcn_mfma_f32_16x16x32_bf16(
                            af[i], bf[j], acc[i][j], 0, 0, 0);
            }
            __syncthreads();
        }
    }

    // C/D layout 16x16: col = lane&15, row = (lane>>4)*4 + q
    int cr = kb * 4;
    #pragma unroll
    for (int i = 0; i < 4; i++) {
        #pragma unroll
        for (int j = 0; j < 4; j++) {
            int col = col0 + wc * 64 + j * 16 + rl;
            float bv = (MODE == 1) ? bias[col] : 0.f;
            f32x4 v = acc[i][j];
            #pragma unroll
            for (int q = 0; q < 4; q++) {
                float o = v[q] + bv;
                size_t grow = (size_t)(row0 + wr * 64 + i * 16 + cr + q);
                if (MODE == 1) {
                    o = o > 0.f ? o : __expf(o) - 1.f;
                    ((float*)Cv)[grow * 512 + col] = o;
                } else {
                    ((u16*)Cv)[grow * 512 + col] = f2bf(o);
                }
            }
        }
    }

    if (MODE == 2) {
        int h = (col0 >> 6) + wc;
        float as_v[4], ad_v[4];
        #pragma unroll
        for (int j = 0; j < 4; j++) {
            as_v[j] = att_s[h * 64 + j * 16 + rl];
            ad_v[j] = att_d[h * 64 + j * 16 + rl];
        }
        #pragma unroll
        for (int i = 0; i < 4; i++) {
            float ps[4] = {}, pd[4] = {};
            #pragma unroll
            for (int j = 0; j < 4; j++) {
                f32x4 v = acc[i][j];
                #pragma unroll
                for (int q = 0; q < 4; q++) {
                    ps[q] = fmaf(v[q], as_v[j], ps[q]);
                    pd[q] = fmaf(v[q], ad_v[j], pd[q]);
                }
            }
            #pragma unroll
            for (int off = 1; off < 16; off <<= 1) {
                #pragma unroll
                for (int q = 0; q < 4; q++) {
                    ps[q] += __shfl_xor(ps[q], off);
                    pd[q] += __shfl_xor(pd[q], off);
                }
            }
            if (rl == 0) {
                #pragma unroll
                for (int q = 0; q < 4; q++) {
                    size_t row = (size_t)(row0 + wr * 64 + i * 16 + cr + q);
                    as_[row * 8 + h] = ps[q];
                    ad_[row * 8 + h] = pd[q];
                }
            }
        }
    }
}

// ------------------------------ attention ---------------------------------
__global__ __launch_bounds__(256) void prep1_k(const float* __restrict__ W1,
                                               const float* __restrict__ as1,
                                               const float* __restrict__ ad1,
                                               float* __restrict__ ws1,
                                               float* __restrict__ wd1) {
    int k = blockIdx.x;
    int t = threadIdx.x;
    int h = t >> 5, lane = t & 31;
    float ps = 0.f, pd = 0.f;
    for (int c = lane; c < 512; c += 32) {
        float w = W1[(size_t)k * 4096 + h * 512 + c];
        ps += w * as1[h * 512 + c];
        pd += w * ad1[h * 512 + c];
    }
    #pragma unroll
    for (int off = 1; off < 32; off <<= 1) {
        ps += __shfl_xor(ps, off);
        pd += __shfl_xor(pd, off);
    }
    if (lane == 0) {
        ws1[k * 8 + h] = ps;
        wd1[k * 8 + h] = pd;
    }
}

// ---------------------------------------------------------------------------
// node0w: ONE WAVE PER NODE. h0 bf16. Lane l: softmax head h=l>>3 (edge
// stripe l&7); aggregates channels 8l..8l+7. Batched two-pass softmax;
// HOISTED per-chunk alpha staging (al_s[wid][MXIT][64] written up front --
// aggregate loop is write-free and fully pipelineable); packed f32x2 FMA.
// ---------------------------------------------------------------------------
__global__ __launch_bounds__(256) void node0w_k(
    const u16* __restrict__ h0b, const float* __restrict__ asrc,
    const float* __restrict__ adst, const int* __restrict__ indptr,
    const int* __restrict__ csr, const float* __restrict__ b0,
    const float* __restrict__ ws1, const float* __restrict__ wd1,
    u16* __restrict__ hl0b, float* __restrict__ as1, float* __restrict__ ad1) {
    __shared__ float al_s[4][MXIT][64];
    __shared__ float red_s[4][16][68];
    int b = blockIdx.x;
    int wid = threadIdx.x >> 6;
    int l = threadIdx.x & 63;
    int d = (b & 7) * (NNODES / 8) + ((b >> 3) << 2) + wid;  // XCD-pinned
    int h = l >> 3;
    int str = l & 7;               // edge stripe
    int e0 = indptr[d];
    int ne = indptr[d + 1] - e0;   // real edges; e==ne is the self loop
    float adh = adst[d * 8 + h];

    // batched loads: csr (independent), then scores (independent)
    int svs[MXIT];
    float vs[MXIT];
    #pragma unroll
    for (int ii = 0; ii < MXIT; ii++) {
        int e = str + ii * 8;
        if (e <= ne) svs[ii] = (e < ne) ? csr[e0 + e] : d;
    }
    #pragma unroll
    for (int ii = 0; ii < MXIT; ii++) {
        int e = str + ii * 8;
        if (e <= ne) {
            float v = asrc[svs[ii] * 8 + h] + adh;
            vs[ii] = v > 0.f ? v : 0.2f * v;
        }
    }
    float m = -3.0e38f;
    #pragma unroll
    for (int ii = 0; ii < MXIT; ii++)
        if (str + ii * 8 <= ne) m = fmaxf(m, vs[ii]);
    // rare tail (deg > 95): extend max dynamically
    for (int e = str + MXIT * 8; e <= ne; e += 8) {
        int s = (e < ne) ? csr[e0 + e] : d;
        float v = asrc[s * 8 + h] + adh;
        v = v > 0.f ? v : 0.2f * v;
        m = fmaxf(m, v);
    }
    #pragma unroll
    for (int off = 1; off < 8; off <<= 1) m = fmaxf(m, __shfl_xor(m, off));
    float z = 0.f;
    #pragma unroll
    for (int ii = 0; ii < MXIT; ii++) {
        if (str + ii * 8 <= ne) {
            vs[ii] = __expf(vs[ii] - m);   // cache numerator
            z += vs[ii];
        }
    }
    for (int e = str + MXIT * 8; e <= ne; e += 8) {
        int s = (e < ne) ? csr[e0 + e] : d;
        float v = asrc[s * 8 + h] + adh;
        v = v > 0.f ? v : 0.2f * v;
        z += __expf(v - m);
    }
    #pragma unroll
    for (int off = 1; off < 8; off <<= 1) z += __shfl_xor(z, off);
    float rz = 1.0f / (z + 1e-16f);

    // hoisted alpha staging: all chunks written before the aggregate loop
    #pragma unroll
    for (int ii = 0; ii < MXIT; ii++)
        if (ii * 8 <= ne) al_s[wid][ii][str * 8 + h] = vs[ii] * rz;

    // aggregate: write-free loop; packed f32x2 FMA
    f32x2 acc2[4] = {};
    #pragma unroll
    for (int ii = 0; ii < MXIT; ii++) {
        int eb = ii * 8;
        if (eb <= ne) {
            int nn = min(8, ne + 1 - eb);
            int sv = svs[ii];
            #pragma unroll
            for (int i = 0; i < 8; i++) {
                if (i < nn) {
                    int s = __shfl(sv, (l & 56) | i);
                    float a = al_s[wid][ii][i * 8 + h];
                    f32x2 a2 = {a, a};
                    int4 pv = *(const int4*)(h0b + ((size_t)s << 9) + 8 * l);
                    f32x2 p01 = {bflo(pv.x), bfhi(pv.x)};
                    f32x2 p23 = {bflo(pv.y), bfhi(pv.y)};
                    f32x2 p45 = {bflo(pv.z), bfhi(pv.z)};
                    f32x2 p67 = {bflo(pv.w), bfhi(pv.w)};
                    acc2[0] = pkfma(a2, p01, acc2[0]);
                    acc2[1] = pkfma(a2, p23, acc2[1]);
                    acc2[2] = pkfma(a2, p45, acc2[2]);
                    acc2[3] = pkfma(a2, p67, acc2[3]);
                }
            }
        }
    }
    // rare tail (deg > 95): reuses chunk-0 slab (main-loop reads complete)
    for (int eb = MXIT * 8; eb <= ne; eb += 8) {
        int idx = eb + str;
        int sv = (idx < ne) ? csr[e0 + idx] : d;
        {
            float v = asrc[sv * 8 + h] + adh;
            v = v > 0.f ? v : 0.2f * v;
            al_s[wid][0][str * 8 + h] = __expf(v - m) * rz;
        }
        int nn = min(8, ne + 1 - eb);
        #pragma unroll
        for (int i = 0; i < 8; i++) {
            if (i < nn) {
                int s = __shfl(sv, (l & 56) | i);
                float a = al_s[wid][0][i * 8 + h];
                f32x2 a2 = {a, a};
                int4 pv = *(const int4*)(h0b + ((size_t)s << 9) + 8 * l);
                f32x2 p01 = {bflo(pv.x), bfhi(pv.x)};
                f32x2 p23 = {bflo(pv.y), bfhi(pv.y)};
                f32x2 p45 = {bflo(pv.z), bfhi(pv.z)};
                f32x2 p67 = {bflo(pv.w), bfhi(pv.w)};
                acc2[0] = pkfma(a2, p01, acc2[0]);
                acc2[1] = pkfma(a2, p23, acc2[1]);
                acc2[2] = pkfma(a2, p45, acc2[2]);
                acc2[3] = pkfma(a2, p67, acc2[3]);
            }
        }
    }

    const float4* b4 = (const float4*)(b0 + 8 * l);
    float4 bva = b4[0], bvb = b4[1];
    float o[8];
    o[0] = acc2[0][0] + bva.x; o[1] = acc2[0][1] + bva.y;
    o[2] = acc2[1][0] + bva.z; o[3] = acc2[1][1] + bva.w;
    o[4] = acc2[2][0] + bvb.x; o[5] = acc2[2][1] + bvb.y;
    o[6] = acc2[3][0] + bvb.z; o[7] = acc2[3][1] + bvb.w;
    #pragma unroll
    for (int k = 0; k < 8; k++) o[k] = o[k] > 0.f ? o[k] : __expf(o[k]) - 1.f;
    int4 hv;
    hv.x = (int)pack2(o[0], o[1]);
    hv.y = (int)pack2(o[2], o[3]);
    hv.z = (int)pack2(o[4], o[5]);
    hv.w = (int)pack2(o[6], o[7]);
    *(int4*)(hl0b + ((size_t)d << 9) + 8 * l) = hv;

    // fused alpha1: packed partials, LDS transpose, 16 lanes row-sum
    f32x2 ps2[4] = {}, pd2[4] = {};
    #pragma unroll
    for (int k = 0; k < 8; k++) {
        const float4* w4 = (const float4*)(ws1 + (size_t)(8 * l + k) * 8);
        const float4* v4 = (const float4*)(wd1 + (size_t)(8 * l + k) * 8);
        float4 wa = w4[0], wb = w4[1];
        float4 va = v4[0], vb = v4[1];
        f32x2 ok2 = {o[k], o[k]};
        f32x2 wa01 = {wa.x, wa.y}, wa23 = {wa.z, wa.w};
        f32x2 wb01 = {wb.x, wb.y}, wb23 = {wb.z, wb.w};
        f32x2 va01 = {va.x, va.y}, va23 = {va.z, va.w};
        f32x2 vb01 = {vb.x, vb.y}, vb23 = {vb.z, vb.w};
        ps2[0] = pkfma(ok2, wa01, ps2[0]);
        ps2[1] = pkfma(ok2, wa23, ps2[1]);
        ps2[2] = pkfma(ok2, wb01, ps2[2]);
        ps2[3] = pkfma(ok2, wb23, ps2[3]);
        pd2[0] = pkfma(ok2, va01, pd2[0]);
        pd2[1] = pkfma(ok2, va23, pd2[1]);
        pd2[2] = pkfma(ok2, vb01, pd2[2]);
        pd2[3] = pkfma(ok2, vb23, pd2[3]);
    }
    #pragma unroll
    for (int j = 0; j < 8; j++) {
        red_s[wid][j][l] = ps2[j >> 1][j & 1];
        red_s[wid][8 + j][l] = pd2[j >> 1][j & 1];
    }
    if (l < 16) {
        const float4* row = (const float4*)&red_s[wid][l][0];
        float s = 0.f;
        #pragma unroll
        for (int q = 0; q < 16; q++) {
            float4 v = row[q];
            s += (v.x + v.y) + (v.z + v.w);
        }
        if (l < 8) as1[(size_t)d * 8 + l] = s;
        else ad1[(size_t)d * 8 + (l - 8)] = s;
    }
}

// ---------------------------------------------------------------------------
// node1w: ONE WAVE PER NODE. hl0 bf16. Lane l: softmax head hme=l&7 (edge
// stripe l>>3). Batched two-pass softmax; hoisted alpha staging; packed FMA.
// ---------------------------------------------------------------------------
__global__ __launch_bounds__(256) void node1w_k(
    const u16* __restrict__ hl0b, const float* __restrict__ asrc,
    const float* __restrict__ adst, const int* __restrict__ indptr,
    const int* __restrict__ csr, u16* __restrict__ aggh, int base, int ch) {
    __shared__ float al_s[4][MXIT][64];
    int b = blockIdx.x;
    int wid = threadIdx.x >> 6;
    int l = threadIdx.x & 63;
    int dl = (b & 7) * (ch >> 3) + ((b >> 3) << 2) + wid;
    int d = base + dl;
    int hme = l & 7;
    int str = l >> 3;              // edge stripe
    int e0 = indptr[d];
    int ne = indptr[d + 1] - e0;
    float adh = adst[d * 8 + hme];

    int svs[MXIT];
    float vs[MXIT];
    #pragma unroll
    for (int ii = 0; ii < MXIT; ii++) {
        int e = str + ii * 8;
        if (e <= ne) svs[ii] = (e < ne) ? csr[e0 + e] : d;
    }
    #pragma unroll
    for (int ii = 0; ii < MXIT; ii++) {
        int e = str + ii * 8;
        if (e <= ne) {
            float v = asrc[svs[ii] * 8 + hme] + adh;
            vs[ii] = v > 0.f ? v : 0.2f * v;
        }
    }
    float m = -3.0e38f;
    #pragma unroll
    for (int ii = 0; ii < MXIT; ii++)
        if (str + ii * 8 <= ne) m = fmaxf(m, vs[ii]);
    for (int e = str + MXIT * 8; e <= ne; e += 8) {
        int s = (e < ne) ? csr[e0 + e] : d;
        float v = asrc[s * 8 + hme] + adh;
        v = v > 0.f ? v : 0.2f * v;
        m = fmaxf(m, v);
    }
    #pragma unroll
    for (int off = 8; off < 64; off <<= 1) m = fmaxf(m, __shfl_xor(m, off));
    float z = 0.f;
    #pragma unroll
    for (int ii = 0; ii < MXIT; ii++) {
        if (str + ii * 8 <= ne) {
            vs[ii] = __expf(vs[ii] - m);
            z += vs[ii];
        }
    }
    for (int e = str + MXIT * 8; e <= ne; e += 8) {
        int s = (e < ne) ? csr[e0 + e] : d;
        float v = asrc[s * 8 + hme] + adh;
        v = v > 0.f ? v : 0.2f * v;
        z += __expf(v - m);
    }
    #pragma unroll
    for (int off = 8; off < 64; off <<= 1) z += __shfl_xor(z, off);
    float rz = 1.0f / (z + 1e-16f);

    // hoisted alpha staging
    #pragma unroll
    for (int ii = 0; ii < MXIT; ii++)
        if (ii * 8 <= ne) al_s[wid][ii][str * 8 + hme] = vs[ii] * rz;

    f32x2 acc2[8][4] = {};
    #pragma unroll
    for (int ii = 0; ii < MXIT; ii++) {
        int eb = ii * 8;
        if (eb <= ne) {
            int nn = min(8, ne + 1 - eb);
            int sv = svs[ii];
            #pragma unroll
            for (int i = 0; i < 8; i++) {
                if (i < nn) {
                    int s = __shfl(sv, i << 3);
                    const float4* ap = (const float4*)&al_s[wid][ii][i * 8];
                    float4 a0 = ap[0], a1 = ap[1];
                    int4 pv = *(const int4*)(hl0b + ((size_t)s << 9) + 8 * l);
                    f32x2 p01 = {bflo(pv.x), bfhi(pv.x)};
                    f32x2 p23 = {bflo(pv.y), bfhi(pv.y)};
                    f32x2 p45 = {bflo(pv.z), bfhi(pv.z)};
                    f32x2 p67 = {bflo(pv.w), bfhi(pv.w)};
                    float av[8] = {a0.x, a0.y, a0.z, a0.w,
                                   a1.x, a1.y, a1.z, a1.w};
                    #pragma unroll
                    for (int hh = 0; hh < 8; hh++) {
                        f32x2 a2 = {av[hh], av[hh]};
                        acc2[hh][0] = pkfma(a2, p01, acc2[hh][0]);
                        acc2[hh][1] = pkfma(a2, p23, acc2[hh][1]);
                        acc2[hh][2] = pkfma(a2, p45, acc2[hh][2]);
                        acc2[hh][3] = pkfma(a2, p67, acc2[hh][3]);
                    }
                }
            }
        }
    }
    // rare tail (deg > 95): reuses chunk-0 slab (main-loop reads complete)
    for (int eb = MXIT * 8; eb <= ne; eb += 8) {
        int idx = eb + str;
        int sv = (idx < ne) ? csr[e0 + idx] : d;
        {
            float v = asrc[sv * 8 + hme] + adh;
            v = v > 0.f ? v : 0.2f * v;
            al_s[wid][0][str * 8 + hme] = __expf(v - m) * rz;
        }
        int nn = min(8, ne + 1 - eb);
        #pragma unroll
        for (int i = 0; i < 8; i++) {
            if (i < nn) {
                int s = __shfl(sv, i << 3);
                const float4* ap = (const float4*)&al_s[wid][0][i * 8];
                float4 a0 = ap[0], a1 = ap[1];
                int4 pv = *(const int4*)(hl0b + ((size_t)s << 9) + 8 * l);
                f32x2 p01 = {bflo(pv.x), bfhi(pv.x)};
                f32x2 p23 = {bflo(pv.y), bfhi(pv.y)};
                f32x2 p45 = {bflo(pv.z), bfhi(pv.z)};
                f32x2 p67 = {bflo(pv.w), bfhi(pv.w)};
                float av[8] = {a0.x, a0.y, a0.z, a0.w, a1.x, a1.y, a1.z, a1.w};
                #pragma unroll
                for (int hh = 0; hh < 8; hh++) {
                    f32x2 a2 = {av[hh], av[hh]};
                    acc2[hh][0] = pkfma(a2, p01, acc2[hh][0]);
                    acc2[hh][1] = pkfma(a2, p23, acc2[hh][1]);
                    acc2[hh][2] = pkfma(a2, p45, acc2[hh][2]);
                    acc2[hh][3] = pkfma(a2, p67, acc2[hh][3]);
                }
            }
        }
    }

    #pragma unroll
    for (int hh = 0; hh < 8; hh++) {
        int4 q;
        q.x = (int)(((u32)f2bf(acc2[hh][0][0])) |
                    ((u32)f2bf(acc2[hh][0][1]) << 16));
        q.y = (int)(((u32)f2bf(acc2[hh][1][0])) |
                    ((u32)f2bf(acc2[hh][1][1]) << 16));
        q.z = (int)(((u32)f2bf(acc2[hh][2][0])) |
                    ((u32)f2bf(acc2[hh][2][1]) << 16));
        q.w = (int)(((u32)f2bf(acc2[hh][3][0])) |
                    ((u32)f2bf(acc2[hh][3][1]) << 16));
        size_t ob = (size_t)dl * 4096 + hh * 512 + 8 * l;
        *(int4*)(aggh + ob) = q;
    }
}

// ------------------------------- launcher ----------------------------------
extern "C" void kernel_launch(void* const* d_in, const int* in_sizes, int n_in,
                              void* d_out, int out_size, void* d_ws, size_t ws_size,
                              hipStream_t stream) {
    const float* x = (const float*)d_in[0];
    const int* ei = (const int*)d_in[1];
    const float* W0 = (const float*)d_in[2];
    const float* at_s0 = (const float*)d_in[3];
    const float* at_d0 = (const float*)d_in[4];
    const float* b0 = (const float*)d_in[5];
    const float* W1 = (const float*)d_in[6];
    const float* at_s1 = (const float*)d_in[7];
    const float* at_d1 = (const float*)d_in[8];
    const float* b1 = (const float*)d_in[9];
    float* out = (float*)d_out;

    const int N = NNODES;
    const int E = in_sizes[1] / 2;
    const int* esrc = ei;
    const int* edst = ei + E;

    char* p = (char*)d_ws;
    auto carve = [&](size_t bytes) -> void* {
        void* r = (void*)p;
        p += ((bytes + 255) & ~(size_t)255);
        return r;
    };
    u16* h0b = (u16*)carve((size_t)N * 512 * 2);
    u16* hl0b = (u16*)carve((size_t)N * 512 * 2);
    float* as0 = (float*)carve((size_t)N * 8 * 4);
    float* ad0 = (float*)carve((size_t)N * 8 * 4);
    float* as1 = (float*)carve((size_t)N * 8 * 4);
    float* ad1 = (float*)carve((size_t)N * 8 * 4);
    int* deg = (int*)carve((size_t)N * 4);
    int* indptr = (int*)carve((size_t)(N + 1) * 4);
    int* cursor = (int*)carve((size_t)N * 4);
    int* csr = (int*)carve((size_t)E * 4);
    float* ws1 = (float*)carve(512 * 8 * 4);
    float* wd1 = (float*)carve(512 * 8 * 4);
    u16* xh = (u16*)carve((size_t)N * 512 * 2);
    u16* xl = (u16*)carve((size_t)N * 512 * 2);
    u16* W0h = (u16*)carve((size_t)512 * 512 * 2);
    u16* W0l = (u16*)carve((size_t)512 * 512 * 2);
    u16* B1h = (u16*)carve((size_t)512 * 4096 * 2);
    size_t used = (size_t)(p - (char*)d_ws);

    int CH = 1024;
    const int cands[5] = {16384, 8192, 4096, 2048, 1024};
    for (int ci = 0; ci < 5; ci++) {
        if (ws_size >= used + (size_t)cands[ci] * 8192 + 512) {
            CH = cands[ci];
            break;
        }
    }
    u16* aggh = (u16*)carve((size_t)CH * 4096 * 2);

    // CSR build
    zero_k<<<(N + 255) / 256, 256, 0, stream>>>(deg, N);
    count_k<<<(E + 255) / 256, 256, 0, stream>>>(edst, E, deg);
    scan_k<<<1, 1024, 0, stream>>>(deg, indptr, cursor, N);
    scatter_k<<<(E + 255) / 256, 256, 0, stream>>>(esrc, edst, E, cursor, csr);

    // operand prep + folded layer-1 attention weights
    prepx_k<<<(N * 512 / 4 + 255) / 256, 256, 0, stream>>>(x, xh, xl);
    prepW0t_k<<<64, 256, 0, stream>>>(W0, W0h, W0l);
    prepW1t_k<<<512, 256, 0, stream>>>(W1, B1h);
    prep1_k<<<512, 256, 0, stream>>>(W1, at_s1, at_d1, ws1, wd1);

    // Layer 0: 3-term GEMM (bf16 out) with fused alpha0 epilogue
    mgemm_k<2, 3><<<dim3(4, N / 128), 256, 0, stream>>>(
        xh, xl, W0h, W0l, h0b, 512, nullptr, at_s0, at_d0, as0, ad0);
    node0w_k<<<N / 4, 256, 0, stream>>>(h0b, as0, ad0, indptr, csr, b0, ws1,
                                        wd1, hl0b, as1, ad1);

    // Layer 1: bf16 aggregate per chunk, pure-bf16 BK=64 GEMM (+b1, ELU)
    for (int base = 0; base < N; base += CH) {
        node1w_k<<<CH / 4, 256, 0, stream>>>(hl0b, as1, ad1, indptr, csr, aggh,
                                             base, CH);
        mgemm_k<1, 1><<<dim3(4, CH / 128), 256, 0, stream>>>(
            aggh, nullptr, B1h, nullptr, out + (size_t)base * 512, 4096, b1,
            nullptr, nullptr, nullptr, nullptr);
    }
}

// Round 27
// 370.136 us; speedup vs baseline: 1.0428x; 1.0428x over previous
//
#include <hip/hip_runtime.h>
#include <hip/hip_bf16.h>

// ---------------------------------------------------------------------------
// GAT 2-layer, N=16384 nodes, D=512, H=8, E=524288 edges (+self loops)
// GEMM0: split-bf16 3-term MFMA (BK=32), fused alpha0, bf16 h0 out.
// GEMM1: pure bf16 MFMA, BK=64. Both: bijective XCD tile remap.
// Node kernels: one wave/node, batched two-pass softmax, per-chunk LDS alpha
// staging, packed f32x2 FMA cores (v_pk_fma_f32).
// (Round-25 configuration: measured best 372.3 us. Round-26's hoisted alpha
//  slab cut occupancy 62->38% and regressed -- reverted; per-wave LDS ops are
//  in-order, so there was no WAR stall to remove.)
// ---------------------------------------------------------------------------

#define NNODES 16384
#define MXIT 12   // supports node degree up to 95; guarded tail beyond

typedef unsigned short u16;
typedef unsigned int u32;
typedef __attribute__((ext_vector_type(8))) __bf16 bf16x8;
typedef __attribute__((ext_vector_type(4))) float f32x4;
typedef __attribute__((ext_vector_type(2))) float f32x2;

__device__ __forceinline__ u16 f2bf(float v) {
    u32 u = __builtin_bit_cast(u32, v);
    u32 r = (u + 0x7fffu + ((u >> 16) & 1u)) >> 16;
    return (u16)r;
}
__device__ __forceinline__ float bf2f(u16 s) {
    u32 u = ((u32)s) << 16;
    return __builtin_bit_cast(float, u);
}
__device__ __forceinline__ float bflo(u32 u) {
    return __builtin_bit_cast(float, u << 16);
}
__device__ __forceinline__ float bfhi(u32 u) {
    return __builtin_bit_cast(float, u & 0xffff0000u);
}
__device__ __forceinline__ void split2(float v, u16& h, u16& l) {
    h = f2bf(v);
    l = f2bf(v - bf2f(h));
}
__device__ __forceinline__ u32 pack2(float a, float b) {
    return (u32)f2bf(a) | ((u32)f2bf(b) << 16);
}
__device__ __forceinline__ f32x2 pkfma(f32x2 a, f32x2 b, f32x2 c) {
    return __builtin_elementwise_fma(a, b, c);
}

// async global->LDS, 16B per lane
__device__ __forceinline__ void gload_lds16(const u16* g, u16* l) {
    __builtin_amdgcn_global_load_lds(
        (__attribute__((address_space(1))) void*)(void*)(g),
        (__attribute__((address_space(3))) void*)(void*)(l), 16, 0, 0);
}

// ------------------------------ CSR build ---------------------------------
__global__ void zero_k(int* p, int n) {
    int i = blockIdx.x * 256 + threadIdx.x;
    if (i < n) p[i] = 0;
}

__global__ void count_k(const int* __restrict__ dst, int E, int* __restrict__ deg) {
    int i = blockIdx.x * 256 + threadIdx.x;
    if (i < E) atomicAdd(&deg[dst[i]], 1);
}

__global__ __launch_bounds__(1024) void scan_k(const int* __restrict__ deg,
                                               int* __restrict__ indptr,
                                               int* __restrict__ cursor, int n) {
    __shared__ int sums[1024];
    int t = threadIdx.x;
    int base = t * 16;
    int local[16];
    int s = 0;
    #pragma unroll
    for (int i = 0; i < 16; i++) { local[i] = s; s += deg[base + i]; }
    sums[t] = s;
    __syncthreads();
    for (int off = 1; off < 1024; off <<= 1) {
        int v = (t >= off) ? sums[t - off] : 0;
        __syncthreads();
        sums[t] += v;
        __syncthreads();
    }
    int base_sum = (t == 0) ? 0 : sums[t - 1];
    #pragma unroll
    for (int i = 0; i < 16; i++) {
        int v = base_sum + local[i];
        indptr[base + i] = v;
        cursor[base + i] = v;
    }
    if (t == 1023) indptr[n] = base_sum + s;
}

__global__ void scatter_k(const int* __restrict__ src, const int* __restrict__ dst,
                          int E, int* __restrict__ cursor, int* __restrict__ csr) {
    int i = blockIdx.x * 256 + threadIdx.x;
    if (i < E) {
        int pos = atomicAdd(&cursor[dst[i]], 1);
        csr[pos] = src[i];
    }
}

// ------------------------- split-bf16 prep kernels -------------------------
__global__ void prepx_k(const float* __restrict__ x, u16* __restrict__ xh,
                        u16* __restrict__ xl) {
    int idx = blockIdx.x * 256 + threadIdx.x;
    int e = idx << 2;
    int n = e >> 9, k = e & 511;
    int g = n >> 10, s = n & 1023;
    float4 v = *(const float4*)(x + ((size_t)(s * 16 + g) << 9) + k);
    u16 h[4], l[4];
    split2(v.x, h[0], l[0]);
    split2(v.y, h[1], l[1]);
    split2(v.z, h[2], l[2]);
    split2(v.w, h[3], l[3]);
    size_t o = ((size_t)n << 9) + k;
    *(ushort4*)(xh + o) = make_ushort4(h[0], h[1], h[2], h[3]);
    *(ushort4*)(xl + o) = make_ushort4(l[0], l[1], l[2], l[3]);
}

// W0t[n][k] = W0[k][n], tiled 64x64 transpose through LDS
__global__ __launch_bounds__(256) void prepW0t_k(const float* __restrict__ W0,
                                                 u16* __restrict__ Wh,
                                                 u16* __restrict__ Wl) {
    __shared__ u32 tile[64][65];
    int b = blockIdx.x;
    int kt = (b >> 3) * 64, nt = (b & 7) * 64;
    int t = threadIdx.x;
    #pragma unroll
    for (int i = 0; i < 16; i++) {
        int idx = i * 256 + t;
        int r = idx >> 6, c = idx & 63;
        float v = W0[(size_t)(kt + r) * 512 + nt + c];
        u16 h, l;
        split2(v, h, l);
        tile[r][c] = ((u32)h << 16) | l;
    }
    __syncthreads();
    #pragma unroll
    for (int i = 0; i < 8; i++) {
        int idx = i * 256 + t;
        int r = idx >> 5, c2 = (idx & 31) * 2;
        u32 p0 = tile[c2][r], p1 = tile[c2 + 1][r];
        size_t o = (size_t)(nt + r) * 512 + kt + c2;
        *(ushort2*)(Wh + o) = make_ushort2((u16)(p0 >> 16), (u16)(p1 >> 16));
        *(ushort2*)(Wl + o) = make_ushort2((u16)(p0 & 0xffff), (u16)(p1 & 0xffff));
    }
}

// B1t[c][h*512+k] = bf16(W1[k][h*512+c]/8), per-head tiled 64x64 transpose
__global__ __launch_bounds__(256) void prepW1t_k(const float* __restrict__ W1,
                                                 u16* __restrict__ Bh) {
    __shared__ u16 tile[64][66];
    int b = blockIdx.x;
    int hh = b >> 6;
    int rem = b & 63;
    int kt = (rem >> 3) * 64, ct = (rem & 7) * 64;
    int t = threadIdx.x;
    #pragma unroll
    for (int i = 0; i < 16; i++) {
        int idx = i * 256 + t;
        int r = idx >> 6, c = idx & 63;
        float v = W1[(size_t)(kt + r) * 4096 + hh * 512 + ct + c] * 0.125f;
        tile[r][c] = f2bf(v);
    }
    __syncthreads();
    #pragma unroll
    for (int i = 0; i < 8; i++) {
        int idx = i * 256 + t;
        int r = idx >> 5, c2 = (idx & 31) * 2;
        size_t o = (size_t)(ct + r) * 4096 + hh * 512 + kt + c2;
        *(ushort2*)(Bh + o) = make_ushort2(tile[c2][r], tile[c2 + 1][r]);
    }
}

// ---------------------------------------------------------------------------
// MFMA GEMM: C[M,512] = A[M,K] @ Bt[512,K]^T, XCD-remapped tiles.
// TERMS=3: split-bf16 3-term, BK=32. TERMS=1: pure bf16, BK=64 (2 halves).
// MODE 1: f32 out, +bias, ELU. MODE 2: bf16 out + fused alpha0.
// ---------------------------------------------------------------------------
template <int MODE, int TERMS>
__global__ __launch_bounds__(256) void mgemm_k(
    const u16* __restrict__ Ah, const u16* __restrict__ Al,
    const u16* __restrict__ Bh, const u16* __restrict__ Bl,
    void* __restrict__ Cv, int K, const float* __restrict__ bias,
    const float* __restrict__ att_s, const float* __restrict__ att_d,
    float* __restrict__ as_, float* __restrict__ ad_) {
    __shared__ u16 smem[16384];  // 32 KB both variants

    int t = threadIdx.x;
    int lane = t & 63, w = t >> 6;
    int wr = w >> 1, wc = w & 1;

    // bijective XCD remap: all 4 col-tiles of a row-tile land on one XCD
    int orig = blockIdx.x + (blockIdx.y << 2);
    int xcd = orig & 7, slot = orig >> 3;
    int by = xcd * ((int)gridDim.y >> 3) + (slot >> 2);
    int bx = slot & 3;
    int row0 = by * 128, col0 = bx * 128;

    f32x4 acc[4][4];
    #pragma unroll
    for (int i = 0; i < 4; i++)
        #pragma unroll
        for (int j = 0; j < 4; j++) acc[i][j] = (f32x4){0.f, 0.f, 0.f, 0.f};

    int srow = lane >> 2;
    int sl4 = lane & 3;
    const u16* gp[8];
    u16* lp[8];
    #pragma unroll
    for (int ii = 0; ii < 8; ii++) {
        const u16* gb;
        int g0, koff;
        if (TERMS == 3) {
            gb = (w == 0) ? Ah : (w == 1) ? Al : (w == 2) ? Bh : Bl;
            g0 = (w < 2) ? row0 : col0;
            koff = 0;
        } else {
            gb = (w < 2) ? Ah : Bh;
            g0 = (w < 2) ? row0 : col0;
            koff = (w & 1) * 32;
        }
        int row = ii * 16 + srow;
        int sslot = sl4 ^ ((row >> 1) & 3);
        gp[ii] = gb + (size_t)(g0 + row) * K + koff + sslot * 8;
        lp[ii] = smem + w * 4096 + ii * 512;
    }

    int rl = lane & 15, kb = lane >> 4;

    if (TERMS == 3) {
        for (int k0 = 0; k0 < K; k0 += 32) {
            #pragma unroll
            for (int ii = 0; ii < 8; ii++) gload_lds16(gp[ii] + k0, lp[ii]);
            __syncthreads();

            bf16x8 afh[4], afl_[4], bfh[4], bfl[4];
            #pragma unroll
            for (int f = 0; f < 4; f++) {
                int r = wr * 64 + f * 16 + rl;
                int off = r * 32 + ((kb ^ ((r >> 1) & 3)) << 3);
                afh[f] = *(const bf16x8*)(smem + off);
                afl_[f] = *(const bf16x8*)(smem + 4096 + off);
            }
            #pragma unroll
            for (int j = 0; j < 4; j++) {
                int r = wc * 64 + j * 16 + rl;
                int off = r * 32 + ((kb ^ ((r >> 1) & 3)) << 3);
                bfh[j] = *(const bf16x8*)(smem + 8192 + off);
                bfl[j] = *(const bf16x8*)(smem + 12288 + off);
            }
            #pragma unroll
            for (int i = 0; i < 4; i++)
                #pragma unroll
                for (int j = 0; j < 4; j++) {
                    acc[i][j] = __builtin_amdgcn_mfma_f32_16x16x32_bf16(
                        afl_[i], bfh[j], acc[i][j], 0, 0, 0);
                    acc[i][j] = __builtin_amdgcn_mfma_f32_16x16x32_bf16(
                        afh[i], bfl[j], acc[i][j], 0, 0, 0);
                    acc[i][j] = __builtin_amdgcn_mfma_f32_16x16x32_bf16(
                        afh[i], bfh[j], acc[i][j], 0, 0, 0);
                }
            __syncthreads();
        }
    } else {
        for (int k0 = 0; k0 < K; k0 += 64) {
            #pragma unroll
            for (int ii = 0; ii < 8; ii++) gload_lds16(gp[ii] + k0, lp[ii]);
            __syncthreads();

            #pragma unroll
            for (int ks = 0; ks < 2; ks++) {
                bf16x8 af[4], bf[4];
                #pragma unroll
                for (int f = 0; f < 4; f++) {
                    int r = wr * 64 + f * 16 + rl;
                    int off = r * 32 + ((kb ^ ((r >> 1) & 3)) << 3);
                    af[f] = *(const bf16x8*)(smem + ks * 4096 + off);
                }
                #pragma unroll
                for (int j = 0; j < 4; j++) {
                    int r = wc * 64 + j * 16 + rl;
                    int off = r * 32 + ((kb ^ ((r >> 1) & 3)) << 3);
                    bf[j] = *(const bf16x8*)(smem + 8192 + ks * 4096 + off);
                }
                #pragma unroll
                for (int i = 0; i < 4; i++)
                    #pragma unroll
                    for (int j = 0; j < 4; j++)
                        acc[i][j] = __builtin_amdgcn_mfma_f32_16x16x32_bf16(
                            af[i], bf[j], acc[i][j], 0, 0, 0);
            }
            __syncthreads();
        }
    }

    // C/D layout 16x16: col = lane&15, row = (lane>>4)*4 + q
    int cr = kb * 4;
    #pragma unroll
    for (int i = 0; i < 4; i++) {
        #pragma unroll
        for (int j = 0; j < 4; j++) {
            int col = col0 + wc * 64 + j * 16 + rl;
            float bv = (MODE == 1) ? bias[col] : 0.f;
            f32x4 v = acc[i][j];
            #pragma unroll
            for (int q = 0; q < 4; q++) {
                float o = v[q] + bv;
                size_t grow = (size_t)(row0 + wr * 64 + i * 16 + cr + q);
                if (MODE == 1) {
                    o = o > 0.f ? o : __expf(o) - 1.f;
                    ((float*)Cv)[grow * 512 + col] = o;
                } else {
                    ((u16*)Cv)[grow * 512 + col] = f2bf(o);
                }
            }
        }
    }

    if (MODE == 2) {
        int h = (col0 >> 6) + wc;
        float as_v[4], ad_v[4];
        #pragma unroll
        for (int j = 0; j < 4; j++) {
            as_v[j] = att_s[h * 64 + j * 16 + rl];
            ad_v[j] = att_d[h * 64 + j * 16 + rl];
        }
        #pragma unroll
        for (int i = 0; i < 4; i++) {
            float ps[4] = {}, pd[4] = {};
            #pragma unroll
            for (int j = 0; j < 4; j++) {
                f32x4 v = acc[i][j];
                #pragma unroll
                for (int q = 0; q < 4; q++) {
                    ps[q] = fmaf(v[q], as_v[j], ps[q]);
                    pd[q] = fmaf(v[q], ad_v[j], pd[q]);
                }
            }
            #pragma unroll
            for (int off = 1; off < 16; off <<= 1) {
                #pragma unroll
                for (int q = 0; q < 4; q++) {
                    ps[q] += __shfl_xor(ps[q], off);
                    pd[q] += __shfl_xor(pd[q], off);
                }
            }
            if (rl == 0) {
                #pragma unroll
                for (int q = 0; q < 4; q++) {
                    size_t row = (size_t)(row0 + wr * 64 + i * 16 + cr + q);
                    as_[row * 8 + h] = ps[q];
                    ad_[row * 8 + h] = pd[q];
                }
            }
        }
    }
}

// ------------------------------ attention ---------------------------------
__global__ __launch_bounds__(256) void prep1_k(const float* __restrict__ W1,
                                               const float* __restrict__ as1,
                                               const float* __restrict__ ad1,
                                               float* __restrict__ ws1,
                                               float* __restrict__ wd1) {
    int k = blockIdx.x;
    int t = threadIdx.x;
    int h = t >> 5, lane = t & 31;
    float ps = 0.f, pd = 0.f;
    for (int c = lane; c < 512; c += 32) {
        float w = W1[(size_t)k * 4096 + h * 512 + c];
        ps += w * as1[h * 512 + c];
        pd += w * ad1[h * 512 + c];
    }
    #pragma unroll
    for (int off = 1; off < 32; off <<= 1) {
        ps += __shfl_xor(ps, off);
        pd += __shfl_xor(pd, off);
    }
    if (lane == 0) {
        ws1[k * 8 + h] = ps;
        wd1[k * 8 + h] = pd;
    }
}

// ---------------------------------------------------------------------------
// node0w: ONE WAVE PER NODE. h0 bf16. Lane l: softmax head h=l>>3 (edge
// stripe l&7); aggregates channels 8l..8l+7. Batched two-pass softmax;
// packed f32x2 FMA core (v_pk_fma_f32) in aggregate + alpha1 epilogue.
// ---------------------------------------------------------------------------
__global__ __launch_bounds__(256) void node0w_k(
    const u16* __restrict__ h0b, const float* __restrict__ asrc,
    const float* __restrict__ adst, const int* __restrict__ indptr,
    const int* __restrict__ csr, const float* __restrict__ b0,
    const float* __restrict__ ws1, const float* __restrict__ wd1,
    u16* __restrict__ hl0b, float* __restrict__ as1, float* __restrict__ ad1) {
    __shared__ float al_s[4][64];
    __shared__ float red_s[4][16][68];
    int b = blockIdx.x;
    int wid = threadIdx.x >> 6;
    int l = threadIdx.x & 63;
    int d = (b & 7) * (NNODES / 8) + ((b >> 3) << 2) + wid;  // XCD-pinned
    int h = l >> 3;
    int str = l & 7;               // edge stripe
    int e0 = indptr[d];
    int ne = indptr[d + 1] - e0;   // real edges; e==ne is the self loop
    float adh = adst[d * 8 + h];

    // batched loads: csr (independent), then scores (independent)
    int svs[MXIT];
    float vs[MXIT];
    #pragma unroll
    for (int ii = 0; ii < MXIT; ii++) {
        int e = str + ii * 8;
        if (e <= ne) svs[ii] = (e < ne) ? csr[e0 + e] : d;
    }
    #pragma unroll
    for (int ii = 0; ii < MXIT; ii++) {
        int e = str + ii * 8;
        if (e <= ne) {
            float v = asrc[svs[ii] * 8 + h] + adh;
            vs[ii] = v > 0.f ? v : 0.2f * v;
        }
    }
    float m = -3.0e38f;
    #pragma unroll
    for (int ii = 0; ii < MXIT; ii++)
        if (str + ii * 8 <= ne) m = fmaxf(m, vs[ii]);
    // rare tail (deg > 95): extend max dynamically
    for (int e = str + MXIT * 8; e <= ne; e += 8) {
        int s = (e < ne) ? csr[e0 + e] : d;
        float v = asrc[s * 8 + h] + adh;
        v = v > 0.f ? v : 0.2f * v;
        m = fmaxf(m, v);
    }
    #pragma unroll
    for (int off = 1; off < 8; off <<= 1) m = fmaxf(m, __shfl_xor(m, off));
    float z = 0.f;
    #pragma unroll
    for (int ii = 0; ii < MXIT; ii++) {
        if (str + ii * 8 <= ne) {
            vs[ii] = __expf(vs[ii] - m);   // cache numerator
            z += vs[ii];
        }
    }
    for (int e = str + MXIT * 8; e <= ne; e += 8) {
        int s = (e < ne) ? csr[e0 + e] : d;
        float v = asrc[s * 8 + h] + adh;
        v = v > 0.f ? v : 0.2f * v;
        z += __expf(v - m);
    }
    #pragma unroll
    for (int off = 1; off < 8; off <<= 1) z += __shfl_xor(z, off);
    float rz = 1.0f / (z + 1e-16f);

    // aggregate: cached svs/vs -> alpha staging; packed f32x2 FMA
    f32x2 acc2[4] = {};
    #pragma unroll
    for (int ii = 0; ii < MXIT; ii++) {
        int eb = ii * 8;
        if (eb <= ne) {
            al_s[wid][str * 8 + h] = vs[ii] * rz;
            int nn = min(8, ne + 1 - eb);
            int sv = svs[ii];
            #pragma unroll
            for (int i = 0; i < 8; i++) {
                if (i < nn) {
                    int s = __shfl(sv, (l & 56) | i);
                    float a = al_s[wid][i * 8 + h];
                    f32x2 a2 = {a, a};
                    int4 pv = *(const int4*)(h0b + ((size_t)s << 9) + 8 * l);
                    f32x2 p01 = {bflo(pv.x), bfhi(pv.x)};
                    f32x2 p23 = {bflo(pv.y), bfhi(pv.y)};
                    f32x2 p45 = {bflo(pv.z), bfhi(pv.z)};
                    f32x2 p67 = {bflo(pv.w), bfhi(pv.w)};
                    acc2[0] = pkfma(a2, p01, acc2[0]);
                    acc2[1] = pkfma(a2, p23, acc2[1]);
                    acc2[2] = pkfma(a2, p45, acc2[2]);
                    acc2[3] = pkfma(a2, p67, acc2[3]);
                }
            }
        }
    }
    // rare tail (deg > 95): old gather path
    for (int eb = MXIT * 8; eb <= ne; eb += 8) {
        int idx = eb + str;
        int sv = (idx < ne) ? csr[e0 + idx] : d;
        {
            float v = asrc[sv * 8 + h] + adh;
            v = v > 0.f ? v : 0.2f * v;
            al_s[wid][str * 8 + h] = __expf(v - m) * rz;
        }
        int nn = min(8, ne + 1 - eb);
        #pragma unroll
        for (int i = 0; i < 8; i++) {
            if (i < nn) {
                int s = __shfl(sv, (l & 56) | i);
                float a = al_s[wid][i * 8 + h];
                f32x2 a2 = {a, a};
                int4 pv = *(const int4*)(h0b + ((size_t)s << 9) + 8 * l);
                f32x2 p01 = {bflo(pv.x), bfhi(pv.x)};
                f32x2 p23 = {bflo(pv.y), bfhi(pv.y)};
                f32x2 p45 = {bflo(pv.z), bfhi(pv.z)};
                f32x2 p67 = {bflo(pv.w), bfhi(pv.w)};
                acc2[0] = pkfma(a2, p01, acc2[0]);
                acc2[1] = pkfma(a2, p23, acc2[1]);
                acc2[2] = pkfma(a2, p45, acc2[2]);
                acc2[3] = pkfma(a2, p67, acc2[3]);
            }
        }
    }

    const float4* b4 = (const float4*)(b0 + 8 * l);
    float4 bva = b4[0], bvb = b4[1];
    float o[8];
    o[0] = acc2[0][0] + bva.x; o[1] = acc2[0][1] + bva.y;
    o[2] = acc2[1][0] + bva.z; o[3] = acc2[1][1] + bva.w;
    o[4] = acc2[2][0] + bvb.x; o[5] = acc2[2][1] + bvb.y;
    o[6] = acc2[3][0] + bvb.z; o[7] = acc2[3][1] + bvb.w;
    #pragma unroll
    for (int k = 0; k < 8; k++) o[k] = o[k] > 0.f ? o[k] : __expf(o[k]) - 1.f;
    int4 hv;
    hv.x = (int)pack2(o[0], o[1]);
    hv.y = (int)pack2(o[2], o[3]);
    hv.z = (int)pack2(o[4], o[5]);
    hv.w = (int)pack2(o[6], o[7]);
    *(int4*)(hl0b + ((size_t)d << 9) + 8 * l) = hv;

    // fused alpha1: packed partials, LDS transpose, 16 lanes row-sum
    f32x2 ps2[4] = {}, pd2[4] = {};
    #pragma unroll
    for (int k = 0; k < 8; k++) {
        const float4* w4 = (const float4*)(ws1 + (size_t)(8 * l + k) * 8);
        const float4* v4 = (const float4*)(wd1 + (size_t)(8 * l + k) * 8);
        float4 wa = w4[0], wb = w4[1];
        float4 va = v4[0], vb = v4[1];
        f32x2 ok2 = {o[k], o[k]};
        f32x2 wa01 = {wa.x, wa.y}, wa23 = {wa.z, wa.w};
        f32x2 wb01 = {wb.x, wb.y}, wb23 = {wb.z, wb.w};
        f32x2 va01 = {va.x, va.y}, va23 = {va.z, va.w};
        f32x2 vb01 = {vb.x, vb.y}, vb23 = {vb.z, vb.w};
        ps2[0] = pkfma(ok2, wa01, ps2[0]);
        ps2[1] = pkfma(ok2, wa23, ps2[1]);
        ps2[2] = pkfma(ok2, wb01, ps2[2]);
        ps2[3] = pkfma(ok2, wb23, ps2[3]);
        pd2[0] = pkfma(ok2, va01, pd2[0]);
        pd2[1] = pkfma(ok2, va23, pd2[1]);
        pd2[2] = pkfma(ok2, vb01, pd2[2]);
        pd2[3] = pkfma(ok2, vb23, pd2[3]);
    }
    #pragma unroll
    for (int j = 0; j < 8; j++) {
        red_s[wid][j][l] = ps2[j >> 1][j & 1];
        red_s[wid][8 + j][l] = pd2[j >> 1][j & 1];
    }
    if (l < 16) {
        const float4* row = (const float4*)&red_s[wid][l][0];
        float s = 0.f;
        #pragma unroll
        for (int q = 0; q < 16; q++) {
            float4 v = row[q];
            s += (v.x + v.y) + (v.z + v.w);
        }
        if (l < 8) as1[(size_t)d * 8 + l] = s;
        else ad1[(size_t)d * 8 + (l - 8)] = s;
    }
}

// ---------------------------------------------------------------------------
// node1w: ONE WAVE PER NODE. hl0 bf16. Lane l: softmax head hme=l&7 (edge
// stripe l>>3). Batched two-pass softmax; packed f32x2 FMA core.
// ---------------------------------------------------------------------------
__global__ __launch_bounds__(256) void node1w_k(
    const u16* __restrict__ hl0b, const float* __restrict__ asrc,
    const float* __restrict__ adst, const int* __restrict__ indptr,
    const int* __restrict__ csr, u16* __restrict__ aggh, int base, int ch) {
    __shared__ float al_s[4][64];
    int b = blockIdx.x;
    int wid = threadIdx.x >> 6;
    int l = threadIdx.x & 63;
    int dl = (b & 7) * (ch >> 3) + ((b >> 3) << 2) + wid;
    int d = base + dl;
    int hme = l & 7;
    int str = l >> 3;              // edge stripe
    int e0 = indptr[d];
    int ne = indptr[d + 1] - e0;
    float adh = adst[d * 8 + hme];

    int svs[MXIT];
    float vs[MXIT];
    #pragma unroll
    for (int ii = 0; ii < MXIT; ii++) {
        int e = str + ii * 8;
        if (e <= ne) svs[ii] = (e < ne) ? csr[e0 + e] : d;
    }
    #pragma unroll
    for (int ii = 0; ii < MXIT; ii++) {
        int e = str + ii * 8;
        if (e <= ne) {
            float v = asrc[svs[ii] * 8 + hme] + adh;
            vs[ii] = v > 0.f ? v : 0.2f * v;
        }
    }
    float m = -3.0e38f;
    #pragma unroll
    for (int ii = 0; ii < MXIT; ii++)
        if (str + ii * 8 <= ne) m = fmaxf(m, vs[ii]);
    for (int e = str + MXIT * 8; e <= ne; e += 8) {
        int s = (e < ne) ? csr[e0 + e] : d;
        float v = asrc[s * 8 + hme] + adh;
        v = v > 0.f ? v : 0.2f * v;
        m = fmaxf(m, v);
    }
    #pragma unroll
    for (int off = 8; off < 64; off <<= 1) m = fmaxf(m, __shfl_xor(m, off));
    float z = 0.f;
    #pragma unroll
    for (int ii = 0; ii < MXIT; ii++) {
        if (str + ii * 8 <= ne) {
            vs[ii] = __expf(vs[ii] - m);
            z += vs[ii];
        }
    }
    for (int e = str + MXIT * 8; e <= ne; e += 8) {
        int s = (e < ne) ? csr[e0 + e] : d;
        float v = asrc[s * 8 + hme] + adh;
        v = v > 0.f ? v : 0.2f * v;
        z += __expf(v - m);
    }
    #pragma unroll
    for (int off = 8; off < 64; off <<= 1) z += __shfl_xor(z, off);
    float rz = 1.0f / (z + 1e-16f);

    f32x2 acc2[8][4] = {};
    #pragma unroll
    for (int ii = 0; ii < MXIT; ii++) {
        int eb = ii * 8;
        if (eb <= ne) {
            al_s[wid][str * 8 + hme] = vs[ii] * rz;
            int nn = min(8, ne + 1 - eb);
            int sv = svs[ii];
            #pragma unroll
            for (int i = 0; i < 8; i++) {
                if (i < nn) {
                    int s = __shfl(sv, i << 3);
                    const float4* ap = (const float4*)&al_s[wid][i * 8];
                    float4 a0 = ap[0], a1 = ap[1];
                    int4 pv = *(const int4*)(hl0b + ((size_t)s << 9) + 8 * l);
                    f32x2 p01 = {bflo(pv.x), bfhi(pv.x)};
                    f32x2 p23 = {bflo(pv.y), bfhi(pv.y)};
                    f32x2 p45 = {bflo(pv.z), bfhi(pv.z)};
                    f32x2 p67 = {bflo(pv.w), bfhi(pv.w)};
                    float av[8] = {a0.x, a0.y, a0.z, a0.w,
                                   a1.x, a1.y, a1.z, a1.w};
                    #pragma unroll
                    for (int hh = 0; hh < 8; hh++) {
                        f32x2 a2 = {av[hh], av[hh]};
                        acc2[hh][0] = pkfma(a2, p01, acc2[hh][0]);
                        acc2[hh][1] = pkfma(a2, p23, acc2[hh][1]);
                        acc2[hh][2] = pkfma(a2, p45, acc2[hh][2]);
                        acc2[hh][3] = pkfma(a2, p67, acc2[hh][3]);
                    }
                }
            }
        }
    }
    // rare tail (deg > 95): old gather path
    for (int eb = MXIT * 8; eb <= ne; eb += 8) {
        int idx = eb + str;
        int sv = (idx < ne) ? csr[e0 + idx] : d;
        {
            float v = asrc[sv * 8 + hme] + adh;
            v = v > 0.f ? v : 0.2f * v;
            al_s[wid][str * 8 + hme] = __expf(v - m) * rz;
        }
        int nn = min(8, ne + 1 - eb);
        #pragma unroll
        for (int i = 0; i < 8; i++) {
            if (i < nn) {
                int s = __shfl(sv, i << 3);
                const float4* ap = (const float4*)&al_s[wid][i * 8];
                float4 a0 = ap[0], a1 = ap[1];
                int4 pv = *(const int4*)(hl0b + ((size_t)s << 9) + 8 * l);
                f32x2 p01 = {bflo(pv.x), bfhi(pv.x)};
                f32x2 p23 = {bflo(pv.y), bfhi(pv.y)};
                f32x2 p45 = {bflo(pv.z), bfhi(pv.z)};
                f32x2 p67 = {bflo(pv.w), bfhi(pv.w)};
                float av[8] = {a0.x, a0.y, a0.z, a0.w, a1.x, a1.y, a1.z, a1.w};
                #pragma unroll
                for (int hh = 0; hh < 8; hh++) {
                    f32x2 a2 = {av[hh], av[hh]};
                    acc2[hh][0] = pkfma(a2, p01, acc2[hh][0]);
                    acc2[hh][1] = pkfma(a2, p23, acc2[hh][1]);
                    acc2[hh][2] = pkfma(a2, p45, acc2[hh][2]);
                    acc2[hh][3] = pkfma(a2, p67, acc2[hh][3]);
                }
            }
        }
    }

    #pragma unroll
    for (int hh = 0; hh < 8; hh++) {
        int4 q;
        q.x = (int)(((u32)f2bf(acc2[hh][0][0])) |
                    ((u32)f2bf(acc2[hh][0][1]) << 16));
        q.y = (int)(((u32)f2bf(acc2[hh][1][0])) |
                    ((u32)f2bf(acc2[hh][1][1]) << 16));
        q.z = (int)(((u32)f2bf(acc2[hh][2][0])) |
                    ((u32)f2bf(acc2[hh][2][1]) << 16));
        q.w = (int)(((u32)f2bf(acc2[hh][3][0])) |
                    ((u32)f2bf(acc2[hh][3][1]) << 16));
        size_t ob = (size_t)dl * 4096 + hh * 512 + 8 * l;
        *(int4*)(aggh + ob) = q;
    }
}

// ------------------------------- launcher ----------------------------------
extern "C" void kernel_launch(void* const* d_in, const int* in_sizes, int n_in,
                              void* d_out, int out_size, void* d_ws, size_t ws_size,
                              hipStream_t stream) {
    const float* x = (const float*)d_in[0];
    const int* ei = (const int*)d_in[1];
    const float* W0 = (const float*)d_in[2];
    const float* at_s0 = (const float*)d_in[3];
    const float* at_d0 = (const float*)d_in[4];
    const float* b0 = (const float*)d_in[5];
    const float* W1 = (const float*)d_in[6];
    const float* at_s1 = (const float*)d_in[7];
    const float* at_d1 = (const float*)d_in[8];
    const float* b1 = (const float*)d_in[9];
    float* out = (float*)d_out;

    const int N = NNODES;
    const int E = in_sizes[1] / 2;
    const int* esrc = ei;
    const int* edst = ei + E;

    char* p = (char*)d_ws;
    auto carve = [&](size_t bytes) -> void* {
        void* r = (void*)p;
        p += ((bytes + 255) & ~(size_t)255);
        return r;
    };
    u16* h0b = (u16*)carve((size_t)N * 512 * 2);
    u16* hl0b = (u16*)carve((size_t)N * 512 * 2);
    float* as0 = (float*)carve((size_t)N * 8 * 4);
    float* ad0 = (float*)carve((size_t)N * 8 * 4);
    float* as1 = (float*)carve((size_t)N * 8 * 4);
    float* ad1 = (float*)carve((size_t)N * 8 * 4);
    int* deg = (int*)carve((size_t)N * 4);
    int* indptr = (int*)carve((size_t)(N + 1) * 4);
    int* cursor = (int*)carve((size_t)N * 4);
    int* csr = (int*)carve((size_t)E * 4);
    float* ws1 = (float*)carve(512 * 8 * 4);
    float* wd1 = (float*)carve(512 * 8 * 4);
    u16* xh = (u16*)carve((size_t)N * 512 * 2);
    u16* xl = (u16*)carve((size_t)N * 512 * 2);
    u16* W0h = (u16*)carve((size_t)512 * 512 * 2);
    u16* W0l = (u16*)carve((size_t)512 * 512 * 2);
    u16* B1h = (u16*)carve((size_t)512 * 4096 * 2);
    size_t used = (size_t)(p - (char*)d_ws);

    int CH = 1024;
    const int cands[5] = {16384, 8192, 4096, 2048, 1024};
    for (int ci = 0; ci < 5; ci++) {
        if (ws_size >= used + (size_t)cands[ci] * 8192 + 512) {
            CH = cands[ci];
            break;
        }
    }
    u16* aggh = (u16*)carve((size_t)CH * 4096 * 2);

    // CSR build
    zero_k<<<(N + 255) / 256, 256, 0, stream>>>(deg, N);
    count_k<<<(E + 255) / 256, 256, 0, stream>>>(edst, E, deg);
    scan_k<<<1, 1024, 0, stream>>>(deg, indptr, cursor, N);
    scatter_k<<<(E + 255) / 256, 256, 0, stream>>>(esrc, edst, E, cursor, csr);

    // operand prep + folded layer-1 attention weights
    prepx_k<<<(N * 512 / 4 + 255) / 256, 256, 0, stream>>>(x, xh, xl);
    prepW0t_k<<<64, 256, 0, stream>>>(W0, W0h, W0l);
    prepW1t_k<<<512, 256, 0, stream>>>(W1, B1h);
    prep1_k<<<512, 256, 0, stream>>>(W1, at_s1, at_d1, ws1, wd1);

    // Layer 0: 3-term GEMM (bf16 out) with fused alpha0 epilogue
    mgemm_k<2, 3><<<dim3(4, N / 128), 256, 0, stream>>>(
        xh, xl, W0h, W0l, h0b, 512, nullptr, at_s0, at_d0, as0, ad0);
    node0w_k<<<N / 4, 256, 0, stream>>>(h0b, as0, ad0, indptr, csr, b0, ws1,
                                        wd1, hl0b, as1, ad1);

    // Layer 1: bf16 aggregate per chunk, pure-bf16 BK=64 GEMM (+b1, ELU)
    for (int base = 0; base < N; base += CH) {
        node1w_k<<<CH / 4, 256, 0, stream>>>(hl0b, as1, ad1, indptr, csr, aggh,
                                             base, CH);
        mgemm_k<1, 1><<<dim3(4, CH / 128), 256, 0, stream>>>(
            aggh, nullptr, B1h, nullptr, out + (size_t)base * 512, 4096, b1,
            nullptr, nullptr, nullptr, nullptr);
    }
}